// Round 2
// baseline (477.846 us; speedup 1.0000x reference)
//
#include <hip/hip_runtime.h>

#define B_ROWS 65536
#define D_IN 784
#define NF 10
#define NLAYERS 62
#define TILE_COLS 28
#define NTILES 28        // 784 / 28
#define BLOCK_A 64       // single-wave blocks: barriers ~free, 4 indep waves/CU
#define GRID_A 1024      // 65536 / 64 rows
#define PAD_COLS 30      // even stride (float2-aligned); worst 5-way write alias, hidden under HBM
#define NSTAT 65         // 10 means + 55 upper-tri second moments
#define QLOADS 7         // 64 rows * 28 cols / 4 floats / 64 threads

// ---------------- pass A: z0 = x @ W0^T + b0, + moment partials ----------------
// writes z0 row-major into d_out (staging), per-block stat partials into ws
__global__ __launch_bounds__(BLOCK_A) void passA(const float* __restrict__ x,
                                                 const float* __restrict__ W0,
                                                 const float* __restrict__ b0,
                                                 float* __restrict__ zout,
                                                 float* __restrict__ partials) {
  __shared__ float xs[BLOCK_A][PAD_COLS];
  const int tid = threadIdx.x;   // == lane (single wave)
  const int rowbase = blockIdx.x * BLOCK_A;
  const float* xblk = x + (size_t)rowbase * D_IN;

  // hoisted load/store index maps (t-invariant)
  int goff[QLOADS], doff[QLOADS];
#pragma unroll
  for (int q = 0; q < QLOADS; ++q) {
    int g = tid + q * BLOCK_A;
    int row = g / 7, pos = g % 7;          // bijection onto [0,64)x[0,7)
    goff[q] = row * D_IN + pos * 4;
    doff[q] = row * PAD_COLS + pos * 4;
  }
  float* xsf = &xs[0][0];

  float acc[NF];
#pragma unroll
  for (int j = 0; j < NF; ++j) acc[j] = b0[j];   // uniform -> s_load

  float4 p[QLOADS];
  // prologue: load tile 0 (coalesced 112B runs per row)
#pragma unroll
  for (int q = 0; q < QLOADS; ++q)
    p[q] = *reinterpret_cast<const float4*>(xblk + goff[q]);
#pragma unroll
  for (int q = 0; q < QLOADS; ++q) {
    float2* dst = reinterpret_cast<float2*>(xsf + doff[q]);
    dst[0] = make_float2(p[q].x, p[q].y);
    dst[1] = make_float2(p[q].z, p[q].w);
  }

  for (int t = 0; t < NTILES; ++t) {
    __syncthreads();               // xs holds tile t
    if (t + 1 < NTILES) {          // prefetch tile t+1 before compute
      const float* src = xblk + (t + 1) * TILE_COLS;
#pragma unroll
      for (int q = 0; q < QLOADS; ++q)
        p[q] = *reinterpret_cast<const float4*>(src + goff[q]);
    }
    const int k0 = t * TILE_COLS;
    float xv[TILE_COLS];
#pragma unroll
    for (int i = 0; i < TILE_COLS; i += 2) {
      float2 v = *reinterpret_cast<const float2*>(&xs[tid][i]);
      xv[i] = v.x; xv[i + 1] = v.y;
    }
#pragma unroll
    for (int i = 0; i < TILE_COLS; ++i) {
#pragma unroll
      for (int j = 0; j < NF; ++j)
        acc[j] = fmaf(xv[i], W0[j * D_IN + k0 + i], acc[j]);  // uniform idx -> s_load
    }
    __syncthreads();               // done reading xs
    if (t + 1 < NTILES) {
#pragma unroll
      for (int q = 0; q < QLOADS; ++q) {
        float2* dst = reinterpret_cast<float2*>(xsf + doff[q]);
        dst[0] = make_float2(p[q].x, p[q].y);
        dst[1] = make_float2(p[q].z, p[q].w);
      }
    }
  }

  // write z0 row (contiguous 40B per lane)
  float* zr = zout + (size_t)(rowbase + tid) * NF;
#pragma unroll
  for (int j = 0; j < NF; j += 2)
    *reinterpret_cast<float2*>(zr + j) = make_float2(acc[j], acc[j + 1]);

  // 65 moments: single-wave butterfly reduce
  float vals[NSTAT];
  {
    int v = 0;
#pragma unroll
    for (int j = 0; j < NF; ++j) vals[v++] = acc[j];
#pragma unroll
    for (int i = 0; i < NF; ++i)
#pragma unroll
      for (int j = i; j < NF; ++j) vals[v++] = acc[i] * acc[j];
  }
#pragma unroll
  for (int k = 0; k < NSTAT; ++k) {
    float s = vals[k];
#pragma unroll
    for (int m = 1; m < 64; m <<= 1) s += __shfl_xor(s, m, 64);
    if (tid == (k & 63)) partials[blockIdx.x * NSTAT + k] = s;
  }
}

// ---------------- pass B: stats recursion + affine composition ----------------
__global__ __launch_bounds__(512) void passB(const float* __restrict__ partials,
                                             const float* __restrict__ g0,
                                             const float* __restrict__ beta0,
                                             const float* __restrict__ Ws,
                                             const float* __restrict__ bs,
                                             const float* __restrict__ gs,
                                             const float* __restrict__ betas,
                                             const float* __restrict__ Wf,
                                             const float* __restrict__ bf,
                                             float* __restrict__ statsf) {
  __shared__ double S[NSTAT], Sp[4][NSTAT];
  __shared__ double M[NF][NF], Cov[NF][NF], P[NF][NF], T[NF][NF], Cz[NF][NF];
  __shared__ double cvec[NF], meanv[NF], muz[NF], czv[NF], sv[NF], tv[NF], mu0[NF];
  __shared__ float Wl[NLAYERS * 100];
  __shared__ float bl[NLAYERS * NF], gl[NLAYERS * NF], bel[NLAYERS * NF];
  const int tid = threadIdx.x;

  for (int i = tid; i < NLAYERS * 100; i += 512) Wl[i] = Ws[i];
  for (int i = tid; i < NLAYERS * NF; i += 512) {
    bl[i] = bs[i]; gl[i] = gs[i]; bel[i] = betas[i];
  }

  if (tid < 4 * NSTAT) {           // 4-way parallel partial reduction
    const int part = tid / NSTAT, k = tid - part * NSTAT;
    double s = 0.0;
    const int b0i = part * (GRID_A / 4);
#pragma unroll 4
    for (int b = 0; b < GRID_A / 4; ++b) s += (double)partials[(b0i + b) * NSTAT + k];
    Sp[part][k] = s;
  }
  __syncthreads();
  if (tid < NSTAT) S[tid] = Sp[0][tid] + Sp[1][tid] + Sp[2][tid] + Sp[3][tid];
  __syncthreads();

  if (tid < NF) mu0[tid] = S[tid] / (double)B_ROWS;
  __syncthreads();
  if (tid < 100) {
    int i = tid / 10, j = tid % 10;
    int a = i < j ? i : j, b2 = i < j ? j : i;
    int idx = 10 + 10 * a - (a * (a - 1)) / 2 + (b2 - a);
    Cov[i][j] = S[idx] / (double)B_ROWS - mu0[i] * mu0[j];
  }
  __syncthreads();
  if (tid < NF) {                  // layer-0 BN
    double s0 = (double)g0[tid] / sqrt(Cov[tid][tid] + 1e-5);
    sv[tid] = s0;
    cvec[tid] = (double)beta0[tid] - s0 * mu0[tid];
    meanv[tid] = (double)beta0[tid];
  }
  __syncthreads();
  if (tid < 100) {
    int i = tid / 10, j = tid % 10;
    M[i][j] = (i == j) ? sv[j] : 0.0;
    Cov[i][j] = Cov[i][j] * sv[i] * sv[j];
  }
  __syncthreads();

  for (int k = 0; k < NLAYERS; ++k) {
    const float* W = &Wl[k * 100];
    const float* bb = &bl[k * NF];
    const float* gg = &gl[k * NF];
    const float* be = &bel[k * NF];
    if (tid < 100) {
      int i = tid / 10, j = tid % 10;
      double t1 = 0.0, t2 = 0.0;
#pragma unroll
      for (int l = 0; l < 10; ++l) {
        t1 += (double)W[i * 10 + l] * Cov[l][j];   // T = W * Cov
        t2 += M[i][l] * (double)W[j * 10 + l];     // P = M * W^T  (row-vec conv)
      }
      T[i][j] = t1; P[i][j] = t2;
    }
    if (tid >= 128 && tid < 138) {  // other wave, runs in parallel
      int j = tid - 128;
      double m1 = (double)bb[j], c1 = (double)bb[j];
#pragma unroll
      for (int l = 0; l < 10; ++l) {
        m1 += meanv[l] * (double)W[j * 10 + l];
        c1 += cvec[l] * (double)W[j * 10 + l];
      }
      muz[j] = m1; czv[j] = c1;
    }
    __syncthreads();
    if (tid < 100) {
      int i = tid / 10, j = tid % 10;
      double t3 = 0.0;
#pragma unroll
      for (int l = 0; l < 10; ++l) t3 += T[i][l] * (double)W[j * 10 + l];  // Cz = T * W^T
      Cz[i][j] = t3;
    }
    __syncthreads();
    if (tid < NF) {
      double s = (double)gg[tid] / sqrt(Cz[tid][tid] + 1e-5);
      sv[tid] = s;
      tv[tid] = (double)be[tid] - s * muz[tid];
    }
    __syncthreads();
    if (tid < 100) {
      int i = tid / 10, j = tid % 10;
      M[i][j] = P[i][j] * sv[j];
      Cov[i][j] = Cz[i][j] * sv[i] * sv[j];
    }
    if (tid >= 128 && tid < 138) {
      int j = tid - 128;
      cvec[j] = czv[j] * sv[j] + tv[j];
      meanv[j] = (double)be[j];
    }
    __syncthreads();
  }

  // fold final linear Wf, bf
  if (tid < 100) {
    int i = tid / 10, j = tid % 10;
    double t2 = 0.0;
#pragma unroll
    for (int l = 0; l < 10; ++l) t2 += M[i][l] * (double)Wf[j * 10 + l];
    P[i][j] = t2;
  }
  if (tid >= 128 && tid < 138) {
    int j = tid - 128;
    double c1 = (double)bf[j];
#pragma unroll
    for (int l = 0; l < 10; ++l) c1 += cvec[l] * (double)Wf[j * 10 + l];
    czv[j] = c1;
  }
  __syncthreads();
  if (tid < 100) statsf[tid] = (float)P[tid / 10][tid % 10];
  if (tid >= 128 && tid < 138) statsf[100 + (tid - 128)] = (float)czv[tid - 128];
}

// ---------------- pass C: out = z0 @ M + c (in place on d_out) ----------------
__global__ __launch_bounds__(256) void passC(float* __restrict__ z_inout,
                                             const float* __restrict__ statsf) {
  const int r = blockIdx.x * 256 + threadIdx.x;
  float* pz = z_inout + (size_t)r * NF;
  float zr[NF];
#pragma unroll
  for (int j = 0; j < NF; j += 2) {
    float2 v = *reinterpret_cast<const float2*>(pz + j);
    zr[j] = v.x; zr[j + 1] = v.y;
  }
  float acc[NF];
#pragma unroll
  for (int j = 0; j < NF; ++j) acc[j] = statsf[100 + j];   // uniform -> s_load
#pragma unroll
  for (int l = 0; l < NF; ++l)
#pragma unroll
    for (int j = 0; j < NF; ++j)
      acc[j] = fmaf(zr[l], statsf[l * 10 + j], acc[j]);
#pragma unroll
  for (int j = 0; j < NF; j += 2)
    *reinterpret_cast<float2*>(pz + j) = make_float2(acc[j], acc[j + 1]);
}

extern "C" void kernel_launch(void* const* d_in, const int* in_sizes, int n_in,
                              void* d_out, int out_size, void* d_ws, size_t ws_size,
                              hipStream_t stream) {
  const float* x     = (const float*)d_in[0];
  const float* W0    = (const float*)d_in[1];
  const float* b0    = (const float*)d_in[2];
  const float* g0    = (const float*)d_in[3];
  const float* beta0 = (const float*)d_in[4];
  const float* Ws    = (const float*)d_in[5];
  const float* bs    = (const float*)d_in[6];
  const float* gs    = (const float*)d_in[7];
  const float* betas = (const float*)d_in[8];
  const float* Wf    = (const float*)d_in[9];
  const float* bf    = (const float*)d_in[10];
  float* out = (float*)d_out;

  float* partials = (float*)d_ws;                    // 1024 * 65 floats (~266 KB)
  float* statsf   = (float*)d_ws + GRID_A * NSTAT;   // 110 floats (M row-major, then c)

  passA<<<GRID_A, BLOCK_A, 0, stream>>>(x, W0, b0, out, partials);
  passB<<<1, 512, 0, stream>>>(partials, g0, beta0, Ws, bs, gs, betas, Wf, bf, statsf);
  passC<<<256, 256, 0, stream>>>(out, statsf);
}